// Round 9
// baseline (760.359 us; speedup 1.0000x reference)
//
#include <hip/hip_runtime.h>
#include <hip/hip_bf16.h>

#define NS 16384   // batch
#define H 256      // hidden
#define TH 768     // 3H
#define PRED 24    // decode steps
#define LDA 272    // LDS h-tile row stride (shorts); R3-R8-verified
#define WS_NEEDED (425984)

typedef short bf16x8 __attribute__((ext_vector_type(8)));
typedef float floatx4 __attribute__((ext_vector_type(4)));

__device__ __forceinline__ float b2f(unsigned short u) {
    return __uint_as_float(((unsigned int)u) << 16);
}
__device__ __forceinline__ unsigned short f2b(float f) {   // RTN-even bf16
    unsigned int u = __float_as_uint(f);
    return (unsigned short)((u + 0x7FFFu + ((u >> 16) & 1u)) >> 16);
}
__device__ __forceinline__ float fsig(float v) {
    return __builtin_amdgcn_rcpf(1.0f + __expf(-v));
}
__device__ __forceinline__ float ftanh(float v) {
    return 1.0f - 2.0f * __builtin_amdgcn_rcpf(1.0f + __expf(2.0f * v));
}

// ================= prep 1: rank-1 input-proj collapse + small vectors =================
__global__ void prep_proj(const void* __restrict__ WihP, const void* __restrict__ wprojP,
                          const void* __restrict__ bprojP, const void* __restrict__ bihP,
                          const void* __restrict__ bhhP, const void* __restrict__ woutP,
                          const void* __restrict__ boutP,
                          float* __restrict__ u, float* __restrict__ c,
                          float* __restrict__ bhn, float* __restrict__ wo,
                          float* __restrict__ b0) {
    const int j = blockIdx.x;        // 768
    const int lane = threadIdx.x;    // 64
    unsigned long long bm = __ballot(!(fabsf(b2f(((const unsigned short*)WihP)[lane])) <= 0.25f));
    const bool f32in = (bm != 0ull);

    float su = 0.f, sc = 0.f;
    if (f32in) {
        const float* row = (const float*)WihP + (size_t)j * H;
        const float* wp = (const float*)wprojP;
        const float* bp = (const float*)bprojP;
        for (int k = lane; k < H; k += 64) {
            float w = row[k];
            su = fmaf(w, wp[k], su); sc = fmaf(w, bp[k], sc);
        }
    } else {
        const unsigned short* row = (const unsigned short*)WihP + (size_t)j * H;
        const unsigned short* wp = (const unsigned short*)wprojP;
        const unsigned short* bp = (const unsigned short*)bprojP;
        for (int k = lane; k < H; k += 64) {
            float w = b2f(row[k]);
            su = fmaf(w, b2f(wp[k]), su); sc = fmaf(w, b2f(bp[k]), sc);
        }
    }
    for (int m = 32; m; m >>= 1) { su += __shfl_xor(su, m, 64); sc += __shfl_xor(sc, m, 64); }

    if (lane == 0) {
        float bih = f32in ? ((const float*)bihP)[j] : b2f(((const unsigned short*)bihP)[j]);
        float bhh = f32in ? ((const float*)bhhP)[j] : b2f(((const unsigned short*)bhhP)[j]);
        u[j] = su;
        c[j] = sc + bih + (j < 512 ? bhh : 0.f);
        if (j >= 512) bhn[j - 512] = bhh;
    }
    if (j < H && lane == 1)
        wo[j] = f32in ? ((const float*)woutP)[j] : b2f(((const unsigned short*)woutP)[j]);
    if (j == 0 && lane == 2)
        b0[0] = f32in ? ((const float*)boutP)[0] : b2f(((const unsigned short*)boutP)[0]);
}

// ======== prep 2: swizzle W_hh into MFMA-frag-contiguous bf16 for the 8-wave map ========
// frag fi = ((w*8 + kk)*3 + g)*2 + s ; within frag: lane*8 shorts.
// Wp[fi*512 + lane*8 + e] = W_hh[(g*256 + s*128 + w*16 + (lane&15))*256 + kk*32 + (lane>>4)*8 + e]
__global__ void prep_swz2(const void* __restrict__ WhhP, unsigned short* __restrict__ Wp) {
    const int cidx = blockIdx.x * 256 + threadIdx.x;   // 24576 chunks of 8 shorts
    unsigned long long bm = __ballot(!(fabsf(b2f(((const unsigned short*)WhhP)[threadIdx.x & 63])) <= 0.25f));
    const bool f32in = (bm != 0ull);

    const int lane = cidx & 63;
    const int fi   = cidx >> 6;         // 384 frags
    const int s    = fi & 1;
    const int g    = (fi >> 1) % 3;
    const int kk   = ((fi >> 1) / 3) & 7;
    const int w    = (fi >> 1) / 24;
    const size_t src = (size_t)(g * 256 + s * 128 + w * 16 + (lane & 15)) * H
                     + kk * 32 + (lane >> 4) * 8;
    unsigned short* dst = Wp + (size_t)cidx * 8;
    if (f32in) {
        const float* sp = (const float*)WhhP + src;
#pragma unroll
        for (int e = 0; e < 8; ++e) dst[e] = f2b(sp[e]);
    } else {
        const unsigned short* sp = (const unsigned short*)WhhP + src;
#pragma unroll
        for (int e = 0; e < 8; ++e) dst[e] = sp[e];
    }
}

// ========== fused 24-step decode: 2 anti-phase blocks per CU (trans/MFMA overlap) ==========
// 512 blocks x 512 thr (8 waves), 32 rows/block, 2 blocks co-resident per CU.
// While one block runs its transcendental-heavy epilogue, the other block's K-loop
// feeds the MFMA pipe (m114 co-scheduling). Wave w owns h-cols {16w+lo, 128+16w+lo}
// (aligned r/z/n triples -> epilogue wave-local); acc = 48 regs.
__global__ __launch_bounds__(512, 4)
void decode_swz2(const void* __restrict__ encP, const void* __restrict__ WihP,
                 const unsigned short* __restrict__ Wp,
                 const float* __restrict__ u, const float* __restrict__ c,
                 const float* __restrict__ bhnA, const float* __restrict__ woA,
                 const float* __restrict__ b0A, void* __restrict__ outP) {
    __shared__ __align__(16) unsigned short As[32 * LDA];   // 17.4 KB bf16 h tile
    __shared__ float pred_part[8][32];
    __shared__ float pred_fin[32];
    __shared__ float pred_out[32][PRED];                    // 3 KB
    __shared__ int sflag;

    const int tid  = threadIdx.x;
    const int w    = tid >> 6;     // 0..7
    const int lane = tid & 63;
    const int lo   = lane & 15;
    const int quad = lane >> 4;
    const int m0   = blockIdx.x * 32;

    if (tid == 0) sflag = 0;
    __syncthreads();
    if (!(fabsf(b2f(((const unsigned short*)WihP)[tid])) <= 0.25f)) sflag = 1;
    __syncthreads();
    const bool f32in = (sflag != 0);

    const float*          encF = (const float*)encP;
    const unsigned short* encB = (const unsigned short*)encP;

    // stage h0 tile (bf16)
    for (int i = tid; i < 32 * H; i += 512) {
        int r = i >> 8, col = i & 255;
        float hv = f32in ? encF[(size_t)(m0 + r) * H + col] : b2f(encB[(size_t)(m0 + r) * H + col]);
        As[r * LDA + col] = f2b(hv);
    }
    if (tid < 32) pred_fin[tid] = 0.f;   // start token x=0

    // per-lane gate constants for the 2 col-groups jj(s) = s*128 + 16w + lo
    float ur[2], uz[2], un[2], cr[2], cz[2], cn[2], bh[2], wov[2];
#pragma unroll
    for (int s = 0; s < 2; ++s) {
        const int jj = s * 128 + w * 16 + lo;
        ur[s] = u[jj];       uz[s] = u[256 + jj];       un[s] = u[512 + jj];
        cr[s] = c[jj];       cz[s] = c[256 + jj];       cn[s] = c[512 + jj];
        bh[s] = bhnA[jj];    wov[s] = woA[jj];
    }
    const float b0 = b0A[0];

    const unsigned short* wp = Wp + (size_t)w * 24576 + lane * 8;  // + frag*512

    __syncthreads();

#pragma unroll 1
    for (int t = 0; t < PRED; ++t) {
        floatx4 acc[3][2][2];   // [g][s][im]
#pragma unroll
        for (int g = 0; g < 3; ++g)
#pragma unroll
            for (int s = 0; s < 2; ++s)
#pragma unroll
                for (int im = 0; im < 2; ++im) acc[g][s][im] = (floatx4){0.f, 0.f, 0.f, 0.f};

        // ---- K-loop: direct coalesced 1KB frag loads (R4-proven) + MFMA ----
#pragma unroll
        for (int kk = 0; kk < 8; ++kk) {
            bf16x8 b[3][2];
#pragma unroll
            for (int g = 0; g < 3; ++g)
#pragma unroll
                for (int s = 0; s < 2; ++s)
                    b[g][s] = *(const bf16x8*)(wp + (size_t)(((kk * 3 + g) * 2 + s)) * 512);
            bf16x8 a[2];
#pragma unroll
            for (int im = 0; im < 2; ++im)
                a[im] = *(const bf16x8*)&As[(im * 16 + lo) * LDA + kk * 32 + quad * 8];
#pragma unroll
            for (int g = 0; g < 3; ++g)
#pragma unroll
                for (int s = 0; s < 2; ++s)
#pragma unroll
                    for (int im = 0; im < 2; ++im)
                        acc[g][s][im] = __builtin_amdgcn_mfma_f32_16x16x32_bf16(
                            a[im], b[g][s], acc[g][s][im], 0, 0, 0);
        }
        __syncthreads();   // all waves done reading As(t)

        // ---- epilogue: gates + h update + pred partials (R8-verified math) ----
#pragma unroll
        for (int im = 0; im < 2; ++im) {
#pragma unroll
            for (int v = 0; v < 4; ++v) {
                const int row = im * 16 + quad * 4 + v;
                const float xv = pred_fin[row];
                float pv = 0.f;
#pragma unroll
                for (int s = 0; s < 2; ++s) {
                    const int jj = s * 128 + w * 16 + lo;
                    const int hofs = row * LDA + jj;
                    const float hold = b2f(As[hofs]);
                    float r  = fsig(fmaf(xv, ur[s], cr[s]) + acc[0][s][im][v]);
                    float z  = fsig(fmaf(xv, uz[s], cz[s]) + acc[1][s][im][v]);
                    float n  = ftanh(fmaf(xv, un[s], cn[s]) + r * (acc[2][s][im][v] + bh[s]));
                    float hn = fmaf(z, hold - n, n);   // (1-z)*n + z*h
                    As[hofs] = f2b(hn);
                    pv = fmaf(hn, wov[s], pv);
                }
                pv += __shfl_xor(pv, 1, 64);
                pv += __shfl_xor(pv, 2, 64);
                pv += __shfl_xor(pv, 4, 64);
                pv += __shfl_xor(pv, 8, 64);
                if (lo == 0) pred_part[w][row] = pv;
            }
        }
        __syncthreads();   // As(t+1) + partials visible

        // ---- finalize: pred -> feedback + buffered output ----
        if (tid < 32) {
            float pr = b0;
#pragma unroll
            for (int ww = 0; ww < 8; ++ww) pr += pred_part[ww][tid];
            pred_fin[tid] = pr;
            pred_out[tid][t] = pr;
        }
        // next iteration's post-K-loop barrier orders pred_fin/pred_part reuse
    }
    __syncthreads();

    // single coalesced output store
    for (int i = tid; i < 32 * PRED; i += 512) {
        int row = i / PRED, tt = i % PRED;
        float pr = pred_out[row][tt];
        if (f32in) ((float*)outP)[(size_t)(m0 + row) * PRED + tt] = pr;
        else ((unsigned short*)outP)[(size_t)(m0 + row) * PRED + tt] = f2b(pr);
    }
}

// ================= fallback (R3, proven): zero-workspace fused decode =================
__global__ __launch_bounds__(512, 2)
void decode_all(const void* __restrict__ encP,   const void* __restrict__ wprojP,
                const void* __restrict__ bprojP, const void* __restrict__ WihP,
                const void* __restrict__ bihP,   const void* __restrict__ WhhP,
                const void* __restrict__ bhhP,   const void* __restrict__ woutP,
                const void* __restrict__ boutP,  void* __restrict__ outP) {
    __shared__ __align__(16) unsigned short As[64 * LDA];
    __shared__ float u_lds[TH], c_lds[TH];
    __shared__ float bhn_lds[H], wo_lds[H];
    __shared__ float wp_lds[H], bp_lds[H];
    __shared__ float pred_lds[2][64];
    __shared__ int sflag;

    const int tid  = threadIdx.x;
    const int wid  = tid >> 6;
    const int lane = tid & 63;
    const int lo   = lane & 15;
    const int quad = lane >> 4;
    const int rh   = wid & 3;
    const int ch   = wid >> 2;
    const int m0   = blockIdx.x * 64;

    if (tid == 0) sflag = 0;
    __syncthreads();
    if (!(fabsf(b2f(((const unsigned short*)WihP)[tid])) <= 0.25f)) sflag = 1;
    __syncthreads();
    const bool f32in = (sflag != 0);

    const float*          encF = (const float*)encP;
    const unsigned short* encB = (const unsigned short*)encP;
    const unsigned short* WhhB = (const unsigned short*)WhhP;
    const float*          WhhF = (const float*)WhhP;

    if (tid < H) {
        wp_lds[tid] = f32in ? ((const float*)wprojP)[tid] : b2f(((const unsigned short*)wprojP)[tid]);
        bp_lds[tid] = f32in ? ((const float*)bprojP)[tid] : b2f(((const unsigned short*)bprojP)[tid]);
        wo_lds[tid] = f32in ? ((const float*)woutP)[tid]  : b2f(((const unsigned short*)woutP)[tid]);
    }
    __syncthreads();

    for (int j = tid; j < TH; j += 512) {
        float su = 0.f, sc = 0.f;
        if (f32in) {
            const float* row = (const float*)WihP + (size_t)j * H;
            for (int k = 0; k < H; ++k) { float w = row[k]; su = fmaf(w, wp_lds[k], su); sc = fmaf(w, bp_lds[k], sc); }
        } else {
            const unsigned short* row = (const unsigned short*)WihP + (size_t)j * H;
            for (int k = 0; k < H; ++k) { float w = b2f(row[k]); su = fmaf(w, wp_lds[k], su); sc = fmaf(w, bp_lds[k], sc); }
        }
        float bih = f32in ? ((const float*)bihP)[j] : b2f(((const unsigned short*)bihP)[j]);
        float bhh = f32in ? ((const float*)bhhP)[j] : b2f(((const unsigned short*)bhhP)[j]);
        u_lds[j] = su;
        c_lds[j] = sc + bih + (j < 512 ? bhh : 0.f);
        if (j >= 512) bhn_lds[j - 512] = bhh;
    }

    for (int i = tid; i < 64 * H; i += 512) {
        int r = i >> 8, col = i & 255;
        float hv = f32in ? encF[(size_t)(m0 + r) * H + col] : b2f(encB[(size_t)(m0 + r) * H + col]);
        As[r * LDA + col] = f2b(hv);
    }
    float hold[8][4];
#pragma unroll
    for (int s = 0; s < 8; ++s)
#pragma unroll
        for (int v = 0; v < 4; ++v) {
            int row = m0 + rh * 16 + quad * 4 + v;
            int jj  = ch * 128 + s * 16 + lo;
            hold[s][v] = f32in ? encF[(size_t)row * H + jj] : b2f(encB[(size_t)row * H + jj]);
        }
    const float b0 = f32in ? ((const float*)boutP)[0] : b2f(((const unsigned short*)boutP)[0]);

    float xm[4] = {0.f, 0.f, 0.f, 0.f};
    __syncthreads();

    const int aBase = (rh * 16 + lo) * LDA;
    const int wCol0 = ch * 128 + lo;

#pragma unroll 1
    for (int t = 0; t < PRED; ++t) {
        floatx4 acc[3][8];
#pragma unroll
        for (int g = 0; g < 3; ++g)
#pragma unroll
            for (int s = 0; s < 8; ++s) acc[g][s] = (floatx4){0.f, 0.f, 0.f, 0.f};

        if (f32in) {
#pragma unroll 1
            for (int kk = 0; kk < 8; ++kk) {
                bf16x8 a = *(const bf16x8*)&As[aBase + kk * 32 + quad * 8];
#pragma unroll
                for (int g = 0; g < 3; ++g)
#pragma unroll
                    for (int s = 0; s < 8; ++s) {
                        const float* wr = WhhF + (size_t)(g * 256 + wCol0 + s * 16) * H + kk * 32 + quad * 8;
                        float4 w0 = *(const float4*)wr;
                        float4 w1 = *(const float4*)(wr + 4);
                        bf16x8 b;
                        b[0] = (short)f2b(w0.x); b[1] = (short)f2b(w0.y);
                        b[2] = (short)f2b(w0.z); b[3] = (short)f2b(w0.w);
                        b[4] = (short)f2b(w1.x); b[5] = (short)f2b(w1.y);
                        b[6] = (short)f2b(w1.z); b[7] = (short)f2b(w1.w);
                        acc[g][s] = __builtin_amdgcn_mfma_f32_16x16x32_bf16(a, b, acc[g][s], 0, 0, 0);
                    }
            }
        } else {
#pragma unroll 1
            for (int kk = 0; kk < 8; ++kk) {
                bf16x8 a = *(const bf16x8*)&As[aBase + kk * 32 + quad * 8];
#pragma unroll
                for (int g = 0; g < 3; ++g)
#pragma unroll
                    for (int s = 0; s < 8; ++s) {
                        bf16x8 b = *(const bf16x8*)(WhhB + (size_t)(g * 256 + wCol0 + s * 16) * H + kk * 32 + quad * 8);
                        acc[g][s] = __builtin_amdgcn_mfma_f32_16x16x32_bf16(a, b, acc[g][s], 0, 0, 0);
                    }
            }
        }
        __syncthreads();

        float p[4] = {0.f, 0.f, 0.f, 0.f};
#pragma unroll
        for (int s = 0; s < 8; ++s) {
            const int jj = ch * 128 + s * 16 + lo;
            const float urr = u_lds[jj], uzz = u_lds[256 + jj], unn = u_lds[512 + jj];
            const float crr = c_lds[jj], czz = c_lds[256 + jj], cnn = c_lds[512 + jj];
            const float bhn = bhn_lds[jj], wov = wo_lds[jj];
#pragma unroll
            for (int v = 0; v < 4; ++v) {
                const float xv = xm[v];
                float r  = fsig(fmaf(xv, urr, crr) + acc[0][s][v]);
                float z  = fsig(fmaf(xv, uzz, czz) + acc[1][s][v]);
                float n  = ftanh(fmaf(xv, unn, cnn) + r * (acc[2][s][v] + bhn));
                float hn = fmaf(z, hold[s][v] - n, n);
                hold[s][v] = hn;
                As[(rh * 16 + quad * 4 + v) * LDA + jj] = f2b(hn);
                p[v] = fmaf(hn, wov, p[v]);
            }
        }
#pragma unroll
        for (int v = 0; v < 4; ++v) {
            float pv = p[v];
            pv += __shfl_xor(pv, 1, 64);
            pv += __shfl_xor(pv, 2, 64);
            pv += __shfl_xor(pv, 4, 64);
            pv += __shfl_xor(pv, 8, 64);
            if (lo == 0) pred_lds[ch][rh * 16 + quad * 4 + v] = pv;
        }
        __syncthreads();

#pragma unroll
        for (int v = 0; v < 4; ++v) {
            const int ml = rh * 16 + quad * 4 + v;
            xm[v] = b0 + pred_lds[0][ml] + pred_lds[1][ml];
        }
        if (tid < 64) {
            float pr = b0 + pred_lds[0][tid] + pred_lds[1][tid];
            if (f32in) ((float*)outP)[(size_t)(m0 + tid) * PRED + t] = pr;
            else ((unsigned short*)outP)[(size_t)(m0 + tid) * PRED + t] = f2b(pr);
        }
    }
}

extern "C" void kernel_launch(void* const* d_in, const int* in_sizes, int n_in,
                              void* d_out, int out_size, void* d_ws, size_t ws_size,
                              hipStream_t stream) {
    if (ws_size >= (size_t)WS_NEEDED) {
        char* ws = (char*)d_ws;
        unsigned short* Wp = (unsigned short*)ws;          // 393216 B
        float* u   = (float*)(ws + 393216);
        float* c   = (float*)(ws + 396288);
        float* bhn = (float*)(ws + 399360);
        float* wo  = (float*)(ws + 400384);
        float* b0  = (float*)(ws + 401408);
        prep_proj<<<TH, 64, 0, stream>>>(d_in[3], d_in[1], d_in[2], d_in[4], d_in[6],
                                         d_in[7], d_in[8], u, c, bhn, wo, b0);
        prep_swz2<<<96, 256, 0, stream>>>(d_in[5], Wp);
        decode_swz2<<<NS / 32, 512, 0, stream>>>(d_in[0], d_in[3], Wp, u, c, bhn, wo, b0, d_out);
    } else {
        decode_all<<<NS / 64, 512, 0, stream>>>(d_in[0], d_in[1], d_in[2], d_in[3],
                                                d_in[4], d_in[5], d_in[6], d_in[7],
                                                d_in[8], d_out);
    }
}

// Round 10
// 656.708 us; speedup vs baseline: 1.1578x; 1.1578x over previous
//
#include <hip/hip_runtime.h>
#include <hip/hip_bf16.h>

#define NS 16384   // batch
#define H 256      // hidden
#define TH 768     // 3H
#define PRED 24    // decode steps
#define LDA 272    // LDS h-tile row stride (shorts); R3-R9-verified
#define AS_SZ (64 * LDA + 1536)   // padded buffer: 2 buffers + rest => ~88KB => 1 block/CU
#define WS_NEEDED (425984)

typedef short bf16x8 __attribute__((ext_vector_type(8)));
typedef float floatx4 __attribute__((ext_vector_type(4)));

__device__ __forceinline__ float b2f(unsigned short u) {
    return __uint_as_float(((unsigned int)u) << 16);
}
__device__ __forceinline__ unsigned short f2b(float f) {   // RTN-even bf16
    unsigned int u = __float_as_uint(f);
    return (unsigned short)((u + 0x7FFFu + ((u >> 16) & 1u)) >> 16);
}
__device__ __forceinline__ float fsig(float v) {
    return __builtin_amdgcn_rcpf(1.0f + __expf(-v));
}
__device__ __forceinline__ float ftanh(float v) {
    return 1.0f - 2.0f * __builtin_amdgcn_rcpf(1.0f + __expf(2.0f * v));
}

// ================= prep 1: rank-1 input-proj collapse + small vectors =================
__global__ void prep_proj(const void* __restrict__ WihP, const void* __restrict__ wprojP,
                          const void* __restrict__ bprojP, const void* __restrict__ bihP,
                          const void* __restrict__ bhhP, const void* __restrict__ woutP,
                          const void* __restrict__ boutP,
                          float* __restrict__ u, float* __restrict__ c,
                          float* __restrict__ bhn, float* __restrict__ wo,
                          float* __restrict__ b0) {
    const int j = blockIdx.x;        // 768
    const int lane = threadIdx.x;    // 64
    unsigned long long bm = __ballot(!(fabsf(b2f(((const unsigned short*)WihP)[lane])) <= 0.25f));
    const bool f32in = (bm != 0ull);

    float su = 0.f, sc = 0.f;
    if (f32in) {
        const float* row = (const float*)WihP + (size_t)j * H;
        const float* wp = (const float*)wprojP;
        const float* bp = (const float*)bprojP;
        for (int k = lane; k < H; k += 64) {
            float w = row[k];
            su = fmaf(w, wp[k], su); sc = fmaf(w, bp[k], sc);
        }
    } else {
        const unsigned short* row = (const unsigned short*)WihP + (size_t)j * H;
        const unsigned short* wp = (const unsigned short*)wprojP;
        const unsigned short* bp = (const unsigned short*)bprojP;
        for (int k = lane; k < H; k += 64) {
            float w = b2f(row[k]);
            su = fmaf(w, b2f(wp[k]), su); sc = fmaf(w, b2f(bp[k]), sc);
        }
    }
    for (int m = 32; m; m >>= 1) { su += __shfl_xor(su, m, 64); sc += __shfl_xor(sc, m, 64); }

    if (lane == 0) {
        float bih = f32in ? ((const float*)bihP)[j] : b2f(((const unsigned short*)bihP)[j]);
        float bhh = f32in ? ((const float*)bhhP)[j] : b2f(((const unsigned short*)bhhP)[j]);
        u[j] = su;
        c[j] = sc + bih + (j < 512 ? bhh : 0.f);
        if (j >= 512) bhn[j - 512] = bhh;
    }
    if (j < H && lane == 1)
        wo[j] = f32in ? ((const float*)woutP)[j] : b2f(((const unsigned short*)woutP)[j]);
    if (j == 0 && lane == 2)
        b0[0] = f32in ? ((const float*)boutP)[0] : b2f(((const unsigned short*)boutP)[0]);
}

// ================= prep 2: swizzle W_hh into MFMA-frag-contiguous bf16 (R4/R8 map) ======
// frag fi = (w*8 + kk)*3 + g ; within frag: lane*8 shorts.
__global__ void prep_swz(const void* __restrict__ WhhP, unsigned short* __restrict__ Wp) {
    const int cidx = blockIdx.x * 256 + threadIdx.x;
    unsigned long long bm = __ballot(!(fabsf(b2f(((const unsigned short*)WhhP)[threadIdx.x & 63])) <= 0.25f));
    const bool f32in = (bm != 0ull);

    const int lane = cidx & 63;
    const int fi   = cidx >> 6;
    const int g    = fi % 3;
    const int kk   = (fi / 3) & 7;
    const int w    = fi / 24;
    const size_t src = (size_t)(g * 256 + w * 16 + (lane & 15)) * H + kk * 32 + (lane >> 4) * 8;
    unsigned short* dst = Wp + (size_t)cidx * 8;
    if (f32in) {
        const float* s = (const float*)WhhP + src;
#pragma unroll
        for (int e = 0; e < 8; ++e) dst[e] = f2b(s[e]);
    } else {
        const unsigned short* s = (const unsigned short*)WhhP + src;
#pragma unroll
        for (int e = 0; e < 8; ++e) dst[e] = s[e];
    }
}

// ================= prep 3: w_out as an augmented MFMA B-column (n=0) ==================
// wf[kk*512 + lane*8 + e] = (lane&15)==0 ? bf16(wo[kk*32 + (lane>>4)*8 + e]) : 0
__global__ void prep_wof(const float* __restrict__ wo, unsigned short* __restrict__ wf) {
    const int idx = blockIdx.x * 256 + threadIdx.x;   // 4096
    const int kk   = idx >> 9;
    const int lane = (idx >> 3) & 63;
    const int e    = idx & 7;
    unsigned short v = 0;
    if ((lane & 15) == 0) v = f2b(wo[kk * 32 + (lane >> 4) * 8 + e]);
    wf[idx] = v;
}

// ====== fused 24-step decode: double-buffered h, ONE barrier/step, MFMA-fused pred ======
// 256 blocks x 1024 thr (16 waves). Wave w owns h-cols [16w,16w+16); acc = 48+16 regs.
// Epilogue(t) writes h(t+1) to the OTHER As buffer -> no K/epilogue barrier; early
// waves' trans/VALU epilogue overlaps late waves' MFMA/mem K-loop (pipe mixing).
// pred via augmented wo-column MFMA: K-loop(t) yields x(t)=pred(t-1) in-register.
__global__ __launch_bounds__(1024)
void decode_po(const void* __restrict__ encP, const void* __restrict__ WihP,
               const unsigned short* __restrict__ Wp, const unsigned short* __restrict__ wf,
               const float* __restrict__ u, const float* __restrict__ c,
               const float* __restrict__ bhnA, const float* __restrict__ b0A,
               void* __restrict__ outP) {
    __shared__ __align__(16) unsigned short As[2 * AS_SZ];  // ~75KB double-buffered h
    __shared__ float pred_out[64][PRED];                    // 6 KB
    __shared__ int sflag;

    const int tid  = threadIdx.x;
    const int w    = tid >> 6;
    const int lane = tid & 63;
    const int lo   = lane & 15;
    const int quad = lane >> 4;
    const int m0   = blockIdx.x * 64;

    if (tid == 0) sflag = 0;
    __syncthreads();
    if (!(fabsf(b2f(((const unsigned short*)WihP)[tid])) <= 0.25f)) sflag = 1;
    __syncthreads();
    const bool f32in = (sflag != 0);

    const float*          encF = (const float*)encP;
    const unsigned short* encB = (const unsigned short*)encP;

    // stage h0 tile (bf16) into buffer 0
    for (int i = tid; i < 64 * H; i += 1024) {
        int r = i >> 8, col = i & 255;
        float hv = f32in ? encF[(size_t)(m0 + r) * H + col] : b2f(encB[(size_t)(m0 + r) * H + col]);
        As[r * LDA + col] = f2b(hv);
    }

    const int jj = w * 16 + lo;
    const float ur = u[jj], uz = u[256 + jj], un = u[512 + jj];
    const float cr = c[jj], cz = c[256 + jj], cn = c[512 + jj];
    const float bh = bhnA[jj];
    const float b0c = b0A[0];

    const unsigned short* wp = Wp + (size_t)w * 12288 + lane * 8;  // + (kk*3+g)*512
    const unsigned short* wfb = wf + lane * 8;                     // + kk*512

    __syncthreads();

    int p = 0;
#pragma unroll 1
    for (int t = 0; t < PRED; ++t) {
        floatx4 acc[3][4];     // gate accums
        floatx4 woacc[4];      // pred(t-1) accums (col 0 valid)
#pragma unroll
        for (int g = 0; g < 3; ++g)
#pragma unroll
            for (int im = 0; im < 4; ++im) acc[g][im] = (floatx4){0.f, 0.f, 0.f, 0.f};
#pragma unroll
        for (int im = 0; im < 4; ++im) woacc[im] = (floatx4){0.f, 0.f, 0.f, 0.f};

        const unsigned short* Ap = As + p * AS_SZ;
        // ---- K-loop: gates + fused w_out column; no barrier inside ----
#pragma unroll
        for (int kk = 0; kk < 8; ++kk) {
            bf16x8 b[3];
#pragma unroll
            for (int g = 0; g < 3; ++g)
                b[g] = *(const bf16x8*)(wp + (kk * 3 + g) * 512);
            bf16x8 bw = *(const bf16x8*)(wfb + kk * 512);
            bf16x8 a[4];
#pragma unroll
            for (int im = 0; im < 4; ++im)
                a[im] = *(const bf16x8*)&Ap[(im * 16 + lo) * LDA + kk * 32 + quad * 8];
#pragma unroll
            for (int g = 0; g < 3; ++g)
#pragma unroll
                for (int im = 0; im < 4; ++im)
                    acc[g][im] = __builtin_amdgcn_mfma_f32_16x16x32_bf16(a[im], b[g], acc[g][im], 0, 0, 0);
#pragma unroll
            for (int im = 0; im < 4; ++im)
                woacc[im] = __builtin_amdgcn_mfma_f32_16x16x32_bf16(a[im], bw, woacc[im], 0, 0, 0);
        }

        // ---- epilogue (no barrier before it: reads Ap, writes other buffer) ----
        unsigned short* An = As + (p ^ 1) * AS_SZ;
#pragma unroll
        for (int im = 0; im < 4; ++im) {
#pragma unroll
            for (int v = 0; v < 4; ++v) {
                const int row = im * 16 + quad * 4 + v;
                float xv = 0.f;
                if (t > 0) xv = b0c + __shfl(woacc[im][v], quad << 4, 64);
                const float hold = b2f(Ap[row * LDA + jj]);
                float r  = fsig(fmaf(xv, ur, cr) + acc[0][im][v]);
                float z  = fsig(fmaf(xv, uz, cz) + acc[1][im][v]);
                float n  = ftanh(fmaf(xv, un, cn) + r * (acc[2][im][v] + bh));
                float hn = fmaf(z, hold - n, n);   // (1-z)*n + z*h
                An[row * LDA + jj] = f2b(hn);
                if (w == 0 && lo == 0 && t > 0) pred_out[row][t - 1] = xv;
            }
        }
        __syncthreads();   // ONE barrier/step: h(t+1) fully written before next K-loop
        p ^= 1;
    }

    // ---- final pred(23) = h(24)·wo + b0 via wo-only MFMA pass ----
    {
        const unsigned short* Ap = As + p * AS_SZ;
        floatx4 wacc2[4];
#pragma unroll
        for (int im = 0; im < 4; ++im) wacc2[im] = (floatx4){0.f, 0.f, 0.f, 0.f};
#pragma unroll
        for (int kk = 0; kk < 8; ++kk) {
            bf16x8 bw = *(const bf16x8*)(wfb + kk * 512);
#pragma unroll
            for (int im = 0; im < 4; ++im) {
                bf16x8 a = *(const bf16x8*)&Ap[(im * 16 + lo) * LDA + kk * 32 + quad * 8];
                wacc2[im] = __builtin_amdgcn_mfma_f32_16x16x32_bf16(a, bw, wacc2[im], 0, 0, 0);
            }
        }
        if (w == 0 && lo == 0) {
#pragma unroll
            for (int im = 0; im < 4; ++im)
#pragma unroll
                for (int v = 0; v < 4; ++v)
                    pred_out[im * 16 + quad * 4 + v][PRED - 1] = b0c + wacc2[im][v];
        }
    }
    __syncthreads();

    // single coalesced output store
    for (int i = tid; i < 64 * PRED; i += 1024) {
        int row = i / PRED, tt = i % PRED;
        float pr = pred_out[row][tt];
        if (f32in) ((float*)outP)[(size_t)(m0 + row) * PRED + tt] = pr;
        else ((unsigned short*)outP)[(size_t)(m0 + row) * PRED + tt] = f2b(pr);
    }
}

// ================= fallback (R3, proven): zero-workspace fused decode =================
__global__ __launch_bounds__(512, 2)
void decode_all(const void* __restrict__ encP,   const void* __restrict__ wprojP,
                const void* __restrict__ bprojP, const void* __restrict__ WihP,
                const void* __restrict__ bihP,   const void* __restrict__ WhhP,
                const void* __restrict__ bhhP,   const void* __restrict__ woutP,
                const void* __restrict__ boutP,  void* __restrict__ outP) {
    __shared__ __align__(16) unsigned short Asf[64 * LDA];
    __shared__ float u_lds[TH], c_lds[TH];
    __shared__ float bhn_lds[H], wo_lds[H];
    __shared__ float wp_lds[H], bp_lds[H];
    __shared__ float pred_lds[2][64];
    __shared__ int sflag;

    const int tid  = threadIdx.x;
    const int wid  = tid >> 6;
    const int lane = tid & 63;
    const int lo   = lane & 15;
    const int quad = lane >> 4;
    const int rh   = wid & 3;
    const int ch   = wid >> 2;
    const int m0   = blockIdx.x * 64;

    if (tid == 0) sflag = 0;
    __syncthreads();
    if (!(fabsf(b2f(((const unsigned short*)WihP)[tid])) <= 0.25f)) sflag = 1;
    __syncthreads();
    const bool f32in = (sflag != 0);

    const float*          encF = (const float*)encP;
    const unsigned short* encB = (const unsigned short*)encP;
    const unsigned short* WhhB = (const unsigned short*)WhhP;
    const float*          WhhF = (const float*)WhhP;

    if (tid < H) {
        wp_lds[tid] = f32in ? ((const float*)wprojP)[tid] : b2f(((const unsigned short*)wprojP)[tid]);
        bp_lds[tid] = f32in ? ((const float*)bprojP)[tid] : b2f(((const unsigned short*)bprojP)[tid]);
        wo_lds[tid] = f32in ? ((const float*)woutP)[tid]  : b2f(((const unsigned short*)woutP)[tid]);
    }
    __syncthreads();

    for (int j = tid; j < TH; j += 512) {
        float su = 0.f, sc = 0.f;
        if (f32in) {
            const float* row = (const float*)WihP + (size_t)j * H;
            for (int k = 0; k < H; ++k) { float w = row[k]; su = fmaf(w, wp_lds[k], su); sc = fmaf(w, bp_lds[k], sc); }
        } else {
            const unsigned short* row = (const unsigned short*)WihP + (size_t)j * H;
            for (int k = 0; k < H; ++k) { float w = b2f(row[k]); su = fmaf(w, wp_lds[k], su); sc = fmaf(w, bp_lds[k], sc); }
        }
        float bih = f32in ? ((const float*)bihP)[j] : b2f(((const unsigned short*)bihP)[j]);
        float bhh = f32in ? ((const float*)bhhP)[j] : b2f(((const unsigned short*)bhhP)[j]);
        u_lds[j] = su;
        c_lds[j] = sc + bih + (j < 512 ? bhh : 0.f);
        if (j >= 512) bhn_lds[j - 512] = bhh;
    }

    for (int i = tid; i < 64 * H; i += 512) {
        int r = i >> 8, col = i & 255;
        float hv = f32in ? encF[(size_t)(m0 + r) * H + col] : b2f(encB[(size_t)(m0 + r) * H + col]);
        Asf[r * LDA + col] = f2b(hv);
    }
    float hold[8][4];
#pragma unroll
    for (int s = 0; s < 8; ++s)
#pragma unroll
        for (int v = 0; v < 4; ++v) {
            int row = m0 + rh * 16 + quad * 4 + v;
            int jj  = ch * 128 + s * 16 + lo;
            hold[s][v] = f32in ? encF[(size_t)row * H + jj] : b2f(encB[(size_t)row * H + jj]);
        }
    const float b0 = f32in ? ((const float*)boutP)[0] : b2f(((const unsigned short*)boutP)[0]);

    float xm[4] = {0.f, 0.f, 0.f, 0.f};
    __syncthreads();

    const int aBase = (rh * 16 + lo) * LDA;
    const int wCol0 = ch * 128 + lo;

#pragma unroll 1
    for (int t = 0; t < PRED; ++t) {
        floatx4 acc[3][8];
#pragma unroll
        for (int g = 0; g < 3; ++g)
#pragma unroll
            for (int s = 0; s < 8; ++s) acc[g][s] = (floatx4){0.f, 0.f, 0.f, 0.f};

        if (f32in) {
#pragma unroll 1
            for (int kk = 0; kk < 8; ++kk) {
                bf16x8 a = *(const bf16x8*)&Asf[aBase + kk * 32 + quad * 8];
#pragma unroll
                for (int g = 0; g < 3; ++g)
#pragma unroll
                    for (int s = 0; s < 8; ++s) {
                        const float* wr = WhhF + (size_t)(g * 256 + wCol0 + s * 16) * H + kk * 32 + quad * 8;
                        float4 w0 = *(const float4*)wr;
                        float4 w1 = *(const float4*)(wr + 4);
                        bf16x8 b;
                        b[0] = (short)f2b(w0.x); b[1] = (short)f2b(w0.y);
                        b[2] = (short)f2b(w0.z); b[3] = (short)f2b(w0.w);
                        b[4] = (short)f2b(w1.x); b[5] = (short)f2b(w1.y);
                        b[6] = (short)f2b(w1.z); b[7] = (short)f2b(w1.w);
                        acc[g][s] = __builtin_amdgcn_mfma_f32_16x16x32_bf16(a, b, acc[g][s], 0, 0, 0);
                    }
            }
        } else {
#pragma unroll 1
            for (int kk = 0; kk < 8; ++kk) {
                bf16x8 a = *(const bf16x8*)&Asf[aBase + kk * 32 + quad * 8];
#pragma unroll
                for (int g = 0; g < 3; ++g)
#pragma unroll
                    for (int s = 0; s < 8; ++s) {
                        bf16x8 b = *(const bf16x8*)(WhhB + (size_t)(g * 256 + wCol0 + s * 16) * H + kk * 32 + quad * 8);
                        acc[g][s] = __builtin_amdgcn_mfma_f32_16x16x32_bf16(a, b, acc[g][s], 0, 0, 0);
                    }
            }
        }
        __syncthreads();

        float pp[4] = {0.f, 0.f, 0.f, 0.f};
#pragma unroll
        for (int s = 0; s < 8; ++s) {
            const int jj = ch * 128 + s * 16 + lo;
            const float urr = u_lds[jj], uzz = u_lds[256 + jj], unn = u_lds[512 + jj];
            const float crr = c_lds[jj], czz = c_lds[256 + jj], cnn = c_lds[512 + jj];
            const float bhn = bhn_lds[jj], wov = wo_lds[jj];
#pragma unroll
            for (int v = 0; v < 4; ++v) {
                const float xv = xm[v];
                float r  = fsig(fmaf(xv, urr, crr) + acc[0][s][v]);
                float z  = fsig(fmaf(xv, uzz, czz) + acc[1][s][v]);
                float n  = ftanh(fmaf(xv, unn, cnn) + r * (acc[2][s][v] + bhn));
                float hn = fmaf(z, hold[s][v] - n, n);
                hold[s][v] = hn;
                Asf[(rh * 16 + quad * 4 + v) * LDA + jj] = f2b(hn);
                pp[v] = fmaf(hn, wov, pp[v]);
            }
        }
#pragma unroll
        for (int v = 0; v < 4; ++v) {
            float pv = pp[v];
            pv += __shfl_xor(pv, 1, 64);
            pv += __shfl_xor(pv, 2, 64);
            pv += __shfl_xor(pv, 4, 64);
            pv += __shfl_xor(pv, 8, 64);
            if (lo == 0) pred_lds[ch][rh * 16 + quad * 4 + v] = pv;
        }
        __syncthreads();

#pragma unroll
        for (int v = 0; v < 4; ++v) {
            const int ml = rh * 16 + quad * 4 + v;
            xm[v] = b0 + pred_lds[0][ml] + pred_lds[1][ml];
        }
        if (tid < 64) {
            float pr = b0 + pred_lds[0][tid] + pred_lds[1][tid];
            if (f32in) ((float*)outP)[(size_t)(m0 + tid) * PRED + t] = pr;
            else ((unsigned short*)outP)[(size_t)(m0 + tid) * PRED + t] = f2b(pr);
        }
    }
}

extern "C" void kernel_launch(void* const* d_in, const int* in_sizes, int n_in,
                              void* d_out, int out_size, void* d_ws, size_t ws_size,
                              hipStream_t stream) {
    if (ws_size >= (size_t)WS_NEEDED) {
        char* ws = (char*)d_ws;
        unsigned short* Wp = (unsigned short*)ws;          // 393216 B
        float* u   = (float*)(ws + 393216);                // 3072 B
        float* c   = (float*)(ws + 396288);                // 3072 B
        float* bhn = (float*)(ws + 399360);                // 1024 B
        float* wo  = (float*)(ws + 400384);                // 1024 B
        float* b0  = (float*)(ws + 401408);                // 1024 B
        unsigned short* wf = (unsigned short*)(ws + 402432); // 8192 B
        prep_proj<<<TH, 64, 0, stream>>>(d_in[3], d_in[1], d_in[2], d_in[4], d_in[6],
                                         d_in[7], d_in[8], u, c, bhn, wo, b0);
        prep_swz<<<96, 256, 0, stream>>>(d_in[5], Wp);
        prep_wof<<<16, 256, 0, stream>>>(wo, wf);
        decode_po<<<NS / 64, 1024, 0, stream>>>(d_in[0], d_in[3], Wp, wf, u, c, bhn, b0, d_out);
    } else {
        decode_all<<<NS / 64, 512, 0, stream>>>(d_in[0], d_in[1], d_in[2], d_in[3],
                                                d_in[4], d_in[5], d_in[6], d_in[7],
                                                d_in[8], d_out);
    }
}

// Round 11
// 310.328 us; speedup vs baseline: 2.4502x; 2.1162x over previous
//
#include <hip/hip_runtime.h>
#include <hip/hip_bf16.h>

#define NS 16384   // batch
#define H 256      // hidden
#define TH 768     // 3H
#define PRED 24    // decode steps
#define LDA 272    // LDS h-tile row stride (shorts); R3-R10-verified
#define WS_NEEDED (425984)

typedef short bf16x8 __attribute__((ext_vector_type(8)));
typedef float floatx4 __attribute__((ext_vector_type(4)));

__device__ __forceinline__ float b2f(unsigned short u) {
    return __uint_as_float(((unsigned int)u) << 16);
}
__device__ __forceinline__ unsigned short f2b(float f) {   // RTN-even bf16
    unsigned int u = __float_as_uint(f);
    return (unsigned short)((u + 0x7FFFu + ((u >> 16) & 1u)) >> 16);
}
__device__ __forceinline__ float fsig(float v) {
    return __builtin_amdgcn_rcpf(1.0f + __expf(-v));
}
__device__ __forceinline__ float ftanh(float v) {
    return 1.0f - 2.0f * __builtin_amdgcn_rcpf(1.0f + __expf(2.0f * v));
}

// ================= prep 1: rank-1 input-proj collapse + small vectors =================
__global__ void prep_proj(const void* __restrict__ WihP, const void* __restrict__ wprojP,
                          const void* __restrict__ bprojP, const void* __restrict__ bihP,
                          const void* __restrict__ bhhP, const void* __restrict__ woutP,
                          const void* __restrict__ boutP,
                          float* __restrict__ u, float* __restrict__ c,
                          float* __restrict__ bhn, float* __restrict__ wo,
                          float* __restrict__ b0) {
    const int j = blockIdx.x;        // 768
    const int lane = threadIdx.x;    // 64
    unsigned long long bm = __ballot(!(fabsf(b2f(((const unsigned short*)WihP)[lane])) <= 0.25f));
    const bool f32in = (bm != 0ull);

    float su = 0.f, sc = 0.f;
    if (f32in) {
        const float* row = (const float*)WihP + (size_t)j * H;
        const float* wp = (const float*)wprojP;
        const float* bp = (const float*)bprojP;
        for (int k = lane; k < H; k += 64) {
            float w = row[k];
            su = fmaf(w, wp[k], su); sc = fmaf(w, bp[k], sc);
        }
    } else {
        const unsigned short* row = (const unsigned short*)WihP + (size_t)j * H;
        const unsigned short* wp = (const unsigned short*)wprojP;
        const unsigned short* bp = (const unsigned short*)bprojP;
        for (int k = lane; k < H; k += 64) {
            float w = b2f(row[k]);
            su = fmaf(w, b2f(wp[k]), su); sc = fmaf(w, b2f(bp[k]), sc);
        }
    }
    for (int m = 32; m; m >>= 1) { su += __shfl_xor(su, m, 64); sc += __shfl_xor(sc, m, 64); }

    if (lane == 0) {
        float bih = f32in ? ((const float*)bihP)[j] : b2f(((const unsigned short*)bihP)[j]);
        float bhh = f32in ? ((const float*)bhhP)[j] : b2f(((const unsigned short*)bhhP)[j]);
        u[j] = su;
        c[j] = sc + bih + (j < 512 ? bhh : 0.f);
        if (j >= 512) bhn[j - 512] = bhh;
    }
    if (j < H && lane == 1)
        wo[j] = f32in ? ((const float*)woutP)[j] : b2f(((const unsigned short*)woutP)[j]);
    if (j == 0 && lane == 2)
        b0[0] = f32in ? ((const float*)boutP)[0] : b2f(((const unsigned short*)boutP)[0]);
}

// ======== prep 2: swizzle W_hh into MFMA-frag-contiguous bf16, 8-wave map (R9-verified) ==
// frag fi = ((w*8 + kk)*3 + g)*2 + s ; within frag: lane*8 shorts.
__global__ void prep_swz2(const void* __restrict__ WhhP, unsigned short* __restrict__ Wp) {
    const int cidx = blockIdx.x * 256 + threadIdx.x;   // 24576 chunks of 8 shorts
    unsigned long long bm = __ballot(!(fabsf(b2f(((const unsigned short*)WhhP)[threadIdx.x & 63])) <= 0.25f));
    const bool f32in = (bm != 0ull);

    const int lane = cidx & 63;
    const int fi   = cidx >> 6;         // 384 frags
    const int s    = fi & 1;
    const int g    = (fi >> 1) % 3;
    const int kk   = ((fi >> 1) / 3) & 7;
    const int w    = (fi >> 1) / 24;
    const size_t src = (size_t)(g * 256 + s * 128 + w * 16 + (lane & 15)) * H
                     + kk * 32 + (lane >> 4) * 8;
    unsigned short* dst = Wp + (size_t)cidx * 8;
    if (f32in) {
        const float* sp = (const float*)WhhP + src;
#pragma unroll
        for (int e = 0; e < 8; ++e) dst[e] = f2b(sp[e]);
    } else {
        const unsigned short* sp = (const unsigned short*)WhhP + src;
#pragma unroll
        for (int e = 0; e < 8; ++e) dst[e] = sp[e];
    }
}

// ============ fused 24-step decode: W fully ON-CU (144 VGPR + 12KB LDS per wave) ==========
// 512 blocks x 512 thr (8 waves), 32 rows/block, 1 block/CU (VGPR 256 + LDS 120KB),
// 2 sequential rounds. W loaded ONCE per block: kk0-5 -> 144 regs, kk6-7 -> wave-private
// LDS. Steady-state steps have ZERO global traffic (the R4-R10 W re-stream is gone).
// Geometry + epilogue math identical to R9's verified decode_swz2.
__global__ __launch_bounds__(512, 2)
void decode_wres(const void* __restrict__ encP, const void* __restrict__ WihP,
                 const unsigned short* __restrict__ Wp,
                 const float* __restrict__ u, const float* __restrict__ c,
                 const float* __restrict__ bhnA, const float* __restrict__ woA,
                 const float* __restrict__ b0A, void* __restrict__ outP) {
    __shared__ __align__(16) unsigned short As[32 * LDA];     // 17.4 KB h tile
    __shared__ __align__(16) unsigned short Wl[8][6144];      // 96 KB: kk6-7 W frags, wave-private
    __shared__ float pred_part[8][32];
    __shared__ float pred_fin[32];
    __shared__ float pred_out[32][PRED];                      // 3 KB
    __shared__ int sflag;

    const int tid  = threadIdx.x;
    const int w    = tid >> 6;     // 0..7
    const int lane = tid & 63;
    const int lo   = lane & 15;
    const int quad = lane >> 4;
    const int m0   = blockIdx.x * 32;

    if (tid == 0) sflag = 0;
    __syncthreads();
    if (!(fabsf(b2f(((const unsigned short*)WihP)[tid])) <= 0.25f)) sflag = 1;
    __syncthreads();
    const bool f32in = (sflag != 0);

    const float*          encF = (const float*)encP;
    const unsigned short* encB = (const unsigned short*)encP;

    // stage h0 tile (bf16)
    for (int i = tid; i < 32 * H; i += 512) {
        int r = i >> 8, col = i & 255;
        float hv = f32in ? encF[(size_t)(m0 + r) * H + col] : b2f(encB[(size_t)(m0 + r) * H + col]);
        As[r * LDA + col] = f2b(hv);
    }
    if (tid < 32) pred_fin[tid] = 0.f;   // start token x=0

    // per-lane gate constants, jj(s) = s*128 + 16w + lo (R9-verified)
    float ur[2], uz[2], un[2], cr[2], cz[2], cn[2], bh[2], wov[2];
#pragma unroll
    for (int s = 0; s < 2; ++s) {
        const int jj = s * 128 + w * 16 + lo;
        ur[s] = u[jj];       uz[s] = u[256 + jj];       un[s] = u[512 + jj];
        cr[s] = c[jj];       cz[s] = c[256 + jj];       cn[s] = c[512 + jj];
        bh[s] = bhnA[jj];    wov[s] = woA[jj];
    }
    const float b0 = b0A[0];

    // ---- one-time W residency load ----
    const unsigned short* wp = Wp + (size_t)w * 24576 + lane * 8;  // + frag*512
    bf16x8 bW[6][3][2];                                            // kk0-5: 144 VGPRs
#pragma unroll
    for (int kk = 0; kk < 6; ++kk)
#pragma unroll
        for (int g = 0; g < 3; ++g)
#pragma unroll
            for (int s = 0; s < 2; ++s)
                bW[kk][g][s] = *(const bf16x8*)(wp + (size_t)((kk * 3 + g) * 2 + s) * 512);
#pragma unroll
    for (int kk = 6; kk < 8; ++kk)
#pragma unroll
        for (int g = 0; g < 3; ++g)
#pragma unroll
            for (int s = 0; s < 2; ++s) {
                bf16x8 v = *(const bf16x8*)(wp + (size_t)((kk * 3 + g) * 2 + s) * 512);
                *(bf16x8*)&Wl[w][(((kk - 6) * 3 + g) * 2 + s) * 512 + lane * 8] = v;
            }
    __syncthreads();   // h0 visible (Wl is wave-private, no hazard)

#pragma unroll 1
    for (int t = 0; t < PRED; ++t) {
        floatx4 acc[3][2][2];   // [g][s][im]
#pragma unroll
        for (int g = 0; g < 3; ++g)
#pragma unroll
            for (int s = 0; s < 2; ++s)
#pragma unroll
                for (int im = 0; im < 2; ++im) acc[g][s][im] = (floatx4){0.f, 0.f, 0.f, 0.f};

        // ---- K-loop: zero global traffic; B from regs (kk0-5) / wave-private LDS (kk6-7) ----
#pragma unroll
        for (int kk = 0; kk < 8; ++kk) {
            bf16x8 a[2];
#pragma unroll
            for (int im = 0; im < 2; ++im)
                a[im] = *(const bf16x8*)&As[(im * 16 + lo) * LDA + kk * 32 + quad * 8];
            if (kk < 6) {
#pragma unroll
                for (int g = 0; g < 3; ++g)
#pragma unroll
                    for (int s = 0; s < 2; ++s)
#pragma unroll
                        for (int im = 0; im < 2; ++im)
                            acc[g][s][im] = __builtin_amdgcn_mfma_f32_16x16x32_bf16(
                                a[im], bW[kk][g][s], acc[g][s][im], 0, 0, 0);
            } else {
                bf16x8 b[3][2];
#pragma unroll
                for (int g = 0; g < 3; ++g)
#pragma unroll
                    for (int s = 0; s < 2; ++s)
                        b[g][s] = *(const bf16x8*)&Wl[w][(((kk - 6) * 3 + g) * 2 + s) * 512 + lane * 8];
#pragma unroll
                for (int g = 0; g < 3; ++g)
#pragma unroll
                    for (int s = 0; s < 2; ++s)
#pragma unroll
                        for (int im = 0; im < 2; ++im)
                            acc[g][s][im] = __builtin_amdgcn_mfma_f32_16x16x32_bf16(
                                a[im], b[g][s], acc[g][s][im], 0, 0, 0);
            }
        }
        __syncthreads();   // all waves done reading As(t)

        // ---- epilogue: gates + h update + pred partials (R9-verified math) ----
#pragma unroll
        for (int im = 0; im < 2; ++im) {
#pragma unroll
            for (int v = 0; v < 4; ++v) {
                const int row = im * 16 + quad * 4 + v;
                const float xv = pred_fin[row];
                float pv = 0.f;
#pragma unroll
                for (int s = 0; s < 2; ++s) {
                    const int jj = s * 128 + w * 16 + lo;
                    const int hofs = row * LDA + jj;
                    const float hold = b2f(As[hofs]);
                    float r  = fsig(fmaf(xv, ur[s], cr[s]) + acc[0][s][im][v]);
                    float z  = fsig(fmaf(xv, uz[s], cz[s]) + acc[1][s][im][v]);
                    float n  = ftanh(fmaf(xv, un[s], cn[s]) + r * (acc[2][s][im][v] + bh[s]));
                    float hn = fmaf(z, hold - n, n);   // (1-z)*n + z*h
                    As[hofs] = f2b(hn);
                    pv = fmaf(hn, wov[s], pv);
                }
                pv += __shfl_xor(pv, 1, 64);
                pv += __shfl_xor(pv, 2, 64);
                pv += __shfl_xor(pv, 4, 64);
                pv += __shfl_xor(pv, 8, 64);
                if (lo == 0) pred_part[w][row] = pv;
            }
        }
        __syncthreads();   // As(t+1) + partials visible

        // ---- finalize: pred -> feedback + buffered output ----
        if (tid < 32) {
            float pr = b0;
#pragma unroll
            for (int ww = 0; ww < 8; ++ww) pr += pred_part[ww][tid];
            pred_fin[tid] = pr;
            pred_out[tid][t] = pr;
        }
        // next iteration's post-K barrier orders pred_fin/pred_part reuse
    }
    __syncthreads();

    // single coalesced output store
    for (int i = tid; i < 32 * PRED; i += 512) {
        int row = i / PRED, tt = i % PRED;
        float pr = pred_out[row][tt];
        if (f32in) ((float*)outP)[(size_t)(m0 + row) * PRED + tt] = pr;
        else ((unsigned short*)outP)[(size_t)(m0 + row) * PRED + tt] = f2b(pr);
    }
}

// ================= fallback (R3, proven): zero-workspace fused decode =================
__global__ __launch_bounds__(512, 2)
void decode_all(const void* __restrict__ encP,   const void* __restrict__ wprojP,
                const void* __restrict__ bprojP, const void* __restrict__ WihP,
                const void* __restrict__ bihP,   const void* __restrict__ WhhP,
                const void* __restrict__ bhhP,   const void* __restrict__ woutP,
                const void* __restrict__ boutP,  void* __restrict__ outP) {
    __shared__ __align__(16) unsigned short Asf[64 * LDA];
    __shared__ float u_lds[TH], c_lds[TH];
    __shared__ float bhn_lds[H], wo_lds[H];
    __shared__ float wp_lds[H], bp_lds[H];
    __shared__ float pred_lds[2][64];
    __shared__ int sflag;

    const int tid  = threadIdx.x;
    const int wid  = tid >> 6;
    const int lane = tid & 63;
    const int lo   = lane & 15;
    const int quad = lane >> 4;
    const int rh   = wid & 3;
    const int ch   = wid >> 2;
    const int m0   = blockIdx.x * 64;

    if (tid == 0) sflag = 0;
    __syncthreads();
    if (!(fabsf(b2f(((const unsigned short*)WihP)[tid])) <= 0.25f)) sflag = 1;
    __syncthreads();
    const bool f32in = (sflag != 0);

    const float*          encF = (const float*)encP;
    const unsigned short* encB = (const unsigned short*)encP;
    const unsigned short* WhhB = (const unsigned short*)WhhP;
    const float*          WhhF = (const float*)WhhP;

    if (tid < H) {
        wp_lds[tid] = f32in ? ((const float*)wprojP)[tid] : b2f(((const unsigned short*)wprojP)[tid]);
        bp_lds[tid] = f32in ? ((const float*)bprojP)[tid] : b2f(((const unsigned short*)bprojP)[tid]);
        wo_lds[tid] = f32in ? ((const float*)woutP)[tid]  : b2f(((const unsigned short*)woutP)[tid]);
    }
    __syncthreads();

    for (int j = tid; j < TH; j += 512) {
        float su = 0.f, sc = 0.f;
        if (f32in) {
            const float* row = (const float*)WihP + (size_t)j * H;
            for (int k = 0; k < H; ++k) { float w = row[k]; su = fmaf(w, wp_lds[k], su); sc = fmaf(w, bp_lds[k], sc); }
        } else {
            const unsigned short* row = (const unsigned short*)WihP + (size_t)j * H;
            for (int k = 0; k < H; ++k) { float w = b2f(row[k]); su = fmaf(w, wp_lds[k], su); sc = fmaf(w, bp_lds[k], sc); }
        }
        float bih = f32in ? ((const float*)bihP)[j] : b2f(((const unsigned short*)bihP)[j]);
        float bhh = f32in ? ((const float*)bhhP)[j] : b2f(((const unsigned short*)bhhP)[j]);
        u_lds[j] = su;
        c_lds[j] = sc + bih + (j < 512 ? bhh : 0.f);
        if (j >= 512) bhn_lds[j - 512] = bhh;
    }

    for (int i = tid; i < 64 * H; i += 512) {
        int r = i >> 8, col = i & 255;
        float hv = f32in ? encF[(size_t)(m0 + r) * H + col] : b2f(encB[(size_t)(m0 + r) * H + col]);
        Asf[r * LDA + col] = f2b(hv);
    }
    float hold[8][4];
#pragma unroll
    for (int s = 0; s < 8; ++s)
#pragma unroll
        for (int v = 0; v < 4; ++v) {
            int row = m0 + rh * 16 + quad * 4 + v;
            int jj  = ch * 128 + s * 16 + lo;
            hold[s][v] = f32in ? encF[(size_t)row * H + jj] : b2f(encB[(size_t)row * H + jj]);
        }
    const float b0 = f32in ? ((const float*)boutP)[0] : b2f(((const unsigned short*)boutP)[0]);

    float xm[4] = {0.f, 0.f, 0.f, 0.f};
    __syncthreads();

    const int aBase = (rh * 16 + lo) * LDA;
    const int wCol0 = ch * 128 + lo;

#pragma unroll 1
    for (int t = 0; t < PRED; ++t) {
        floatx4 acc[3][8];
#pragma unroll
        for (int g = 0; g < 3; ++g)
#pragma unroll
            for (int s = 0; s < 8; ++s) acc[g][s] = (floatx4){0.f, 0.f, 0.f, 0.f};

        if (f32in) {
#pragma unroll 1
            for (int kk = 0; kk < 8; ++kk) {
                bf16x8 a = *(const bf16x8*)&Asf[aBase + kk * 32 + quad * 8];
#pragma unroll
                for (int g = 0; g < 3; ++g)
#pragma unroll
                    for (int s = 0; s < 8; ++s) {
                        const float* wr = WhhF + (size_t)(g * 256 + wCol0 + s * 16) * H + kk * 32 + quad * 8;
                        float4 w0 = *(const float4*)wr;
                        float4 w1 = *(const float4*)(wr + 4);
                        bf16x8 b;
                        b[0] = (short)f2b(w0.x); b[1] = (short)f2b(w0.y);
                        b[2] = (short)f2b(w0.z); b[3] = (short)f2b(w0.w);
                        b[4] = (short)f2b(w1.x); b[5] = (short)f2b(w1.y);
                        b[6] = (short)f2b(w1.z); b[7] = (short)f2b(w1.w);
                        acc[g][s] = __builtin_amdgcn_mfma_f32_16x16x32_bf16(a, b, acc[g][s], 0, 0, 0);
                    }
            }
        } else {
#pragma unroll 1
            for (int kk = 0; kk < 8; ++kk) {
                bf16x8 a = *(const bf16x8*)&Asf[aBase + kk * 32 + quad * 8];
#pragma unroll
                for (int g = 0; g < 3; ++g)
#pragma unroll
                    for (int s = 0; s < 8; ++s) {
                        bf16x8 b = *(const bf16x8*)(WhhB + (size_t)(g * 256 + wCol0 + s * 16) * H + kk * 32 + quad * 8);
                        acc[g][s] = __builtin_amdgcn_mfma_f32_16x16x32_bf16(a, b, acc[g][s], 0, 0, 0);
                    }
            }
        }
        __syncthreads();

        float pp[4] = {0.f, 0.f, 0.f, 0.f};
#pragma unroll
        for (int s = 0; s < 8; ++s) {
            const int jj = ch * 128 + s * 16 + lo;
            const float urr = u_lds[jj], uzz = u_lds[256 + jj], unn = u_lds[512 + jj];
            const float crr = c_lds[jj], czz = c_lds[256 + jj], cnn = c_lds[512 + jj];
            const float bhn = bhn_lds[jj], wovv = wo_lds[jj];
#pragma unroll
            for (int v = 0; v < 4; ++v) {
                const float xv = xm[v];
                float r  = fsig(fmaf(xv, urr, crr) + acc[0][s][v]);
                float z  = fsig(fmaf(xv, uzz, czz) + acc[1][s][v]);
                float n  = ftanh(fmaf(xv, unn, cnn) + r * (acc[2][s][v] + bhn));
                float hn = fmaf(z, hold[s][v] - n, n);
                hold[s][v] = hn;
                Asf[(rh * 16 + quad * 4 + v) * LDA + jj] = f2b(hn);
                pp[v] = fmaf(hn, wovv, pp[v]);
            }
        }
#pragma unroll
        for (int v = 0; v < 4; ++v) {
            float pv = pp[v];
            pv += __shfl_xor(pv, 1, 64);
            pv += __shfl_xor(pv, 2, 64);
            pv += __shfl_xor(pv, 4, 64);
            pv += __shfl_xor(pv, 8, 64);
            if (lo == 0) pred_lds[ch][rh * 16 + quad * 4 + v] = pv;
        }
        __syncthreads();

#pragma unroll
        for (int v = 0; v < 4; ++v) {
            const int ml = rh * 16 + quad * 4 + v;
            xm[v] = b0 + pred_lds[0][ml] + pred_lds[1][ml];
        }
        if (tid < 64) {
            float pr = b0 + pred_lds[0][tid] + pred_lds[1][tid];
            if (f32in) ((float*)outP)[(size_t)(m0 + tid) * PRED + t] = pr;
            else ((unsigned short*)outP)[(size_t)(m0 + tid) * PRED + t] = f2b(pr);
        }
    }
}

extern "C" void kernel_launch(void* const* d_in, const int* in_sizes, int n_in,
                              void* d_out, int out_size, void* d_ws, size_t ws_size,
                              hipStream_t stream) {
    if (ws_size >= (size_t)WS_NEEDED) {
        char* ws = (char*)d_ws;
        unsigned short* Wp = (unsigned short*)ws;          // 393216 B
        float* u   = (float*)(ws + 393216);                // 3072 B
        float* c   = (float*)(ws + 396288);                // 3072 B
        float* bhn = (float*)(ws + 399360);                // 1024 B
        float* wo  = (float*)(ws + 400384);                // 1024 B
        float* b0  = (float*)(ws + 401408);                // 4 B
        prep_proj<<<TH, 64, 0, stream>>>(d_in[3], d_in[1], d_in[2], d_in[4], d_in[6],
                                         d_in[7], d_in[8], u, c, bhn, wo, b0);
        prep_swz2<<<96, 256, 0, stream>>>(d_in[5], Wp);
        decode_wres<<<NS / 32, 512, 0, stream>>>(d_in[0], d_in[3], Wp, u, c, bhn, wo, b0, d_out);
    } else {
        decode_all<<<NS / 64, 512, 0, stream>>>(d_in[0], d_in[1], d_in[2], d_in[3],
                                                d_in[4], d_in[5], d_in[6], d_in[7],
                                                d_in[8], d_out);
    }
}